// Round 4
// baseline (289.826 us; speedup 1.0000x reference)
//
#include <hip/hip_runtime.h>

// Problem constants (match reference setup_inputs)
constexpr int N_NODES = 50000;
constexpr int N_EDGES = 25000;
constexpr int C = 256;   // IN == OUT == 256 channels
constexpr int L = 32;    // incidence list width

// Transposed bf16 weights in device globals.
__device__ ushort W1T_g[C * C];   // [n][k] bf16
__device__ ushort W2T_g[C * C];   // [n][k] bf16

// Work-distribution tickets for gather_node (one counter per channel-chunk).
// Zeroed each launch by convert_x_kernel (stream-ordered before gather_node).
__device__ int chunk_cnt_g[4];

// Native clang vector types (usable with nontemporal builtins).
typedef __attribute__((ext_vector_type(8))) short bf16x8;
typedef __attribute__((ext_vector_type(4))) float f32x4;

__device__ __forceinline__ ushort f2bf(float f) {
    union { float f; unsigned int u; } c; c.f = f;
    unsigned int r = c.u + 0x7FFFu + ((c.u >> 16) & 1u);   // RNE
    return (ushort)(r >> 16);
}
// bf16 pair unpack: low half = shift, high half = mask (1 VALU op each)
__device__ __forceinline__ float bflo(unsigned int u) {
    union { unsigned int x; float f; } c; c.x = u << 16; return c.f;
}
__device__ __forceinline__ float bfhi(unsigned int u) {
    union { unsigned int x; float f; } c; c.x = u & 0xFFFF0000u; return c.f;
}
__device__ __forceinline__ void acc_uint4(float* acc, const uint4 v) {
    acc[0] += bflo(v.x); acc[1] += bfhi(v.x);
    acc[2] += bflo(v.y); acc[3] += bfhi(v.y);
    acc[4] += bflo(v.z); acc[5] += bfhi(v.z);
    acc[6] += bflo(v.w); acc[7] += bfhi(v.w);
}

// Physical XCD id of the CU this wave runs on (0..7 on MI355X).
// Verified readable on gfx950 (learn_hip m09). Value only steers the
// work-ticket preference -- correctness does not depend on it.
__device__ __forceinline__ int get_xcc_id() {
    int x;
    asm volatile("s_getreg_b32 %0, hwreg(HW_REG_XCC_ID)" : "=s"(x));
    return x & 7;
}

// ---------------------------------------------------------------------------
// x [N,256] fp32 -> xb bf16. 4 elems/thread. Also zeroes the work counters.
// ---------------------------------------------------------------------------
__global__ __launch_bounds__(256) void convert_x_kernel(
    const float* __restrict__ x, ushort* __restrict__ xb)
{
    if (blockIdx.x == 0 && threadIdx.x < 4) chunk_cnt_g[threadIdx.x] = 0;
    const size_t i = ((size_t)blockIdx.x * 256 + threadIdx.x) * 4;
    const float4 v = *reinterpret_cast<const float4*>(x + i);
    ushort4 o;
    o.x = f2bf(v.x); o.y = f2bf(v.y); o.z = f2bf(v.z); o.w = f2bf(v.w);
    *reinterpret_cast<ushort4*>(xb + i) = o;
}

// ---------------------------------------------------------------------------
// W [256k,256n] fp32 row-major -> WT [n][k] bf16 (transposed), via LDS tile.
// ---------------------------------------------------------------------------
__global__ __launch_bounds__(256) void wconv_kernel(
    const float* __restrict__ W1, const float* __restrict__ W2)
{
    const float* W  = blockIdx.z ? W2 : W1;
    ushort* WT      = blockIdx.z ? W2T_g : W1T_g;
    __shared__ float t[64][65];
    const int rr = threadIdx.x >> 6;    // 0..3
    const int cc = threadIdx.x & 63;    // 0..63
    const int br = blockIdx.x * 64;     // k tile
    const int bc = blockIdx.y * 64;     // n tile
#pragma unroll
    for (int i = 0; i < 16; ++i) {
        const int row = i * 4 + rr;
        t[row][cc] = W[(size_t)(br + row) * C + bc + cc];
    }
    __syncthreads();
#pragma unroll
    for (int i = 0; i < 16; ++i) {
        const int n = i * 4 + rr;
        WT[(size_t)(bc + n) * C + br + cc] = f2bf(t[cc][n]);
    }
}

// ---------------------------------------------------------------------------
// gather_edge (gather1): tmp1[row,:] = avg over valid slots of xb[seq[row,:],:]
// Unchunked: half-wave per row, 512B/row granule. BRANCHLESS: always load
// (id==0 reads row 0 -- valid), then subtract the (L-cnt) spurious row-0
// contributions.
//   cnt>0 : out = (acc - (L-cnt)*x0) / cnt
//   cnt==0: out = acc / L            (== row 0 exactly, matches uniform avg)
// ---------------------------------------------------------------------------
__global__ __launch_bounds__(256) void gather_edge_kernel(
    const ushort* __restrict__ src, const int* __restrict__ idx,
    ushort* __restrict__ dst, int nrows)
{
    const int row = blockIdx.x * 8 + (threadIdx.x >> 5);
    const int ln  = threadIdx.x & 31;
    if (row >= nrows) return;

    const int myid = idx[(size_t)row * L + ln];
    const unsigned long long b = __ballot(myid > 0);
    const unsigned int halfmask = (unsigned int)(b >> (threadIdx.x & 32));
    const int cnt = __popc(halfmask);

    float acc[8] = {0.f, 0.f, 0.f, 0.f, 0.f, 0.f, 0.f, 0.f};
#pragma unroll
    for (int l = 0; l < L; ++l) {
        const int id = __shfl(myid, l, 32);
        const uint4 v = *reinterpret_cast<const uint4*>(
            src + (size_t)id * C + ln * 8);
        acc_uint4(acc, v);
    }
    const uint4 v0 = *reinterpret_cast<const uint4*>(src + ln * 8); // row 0
    float x0[8];
    x0[0] = bflo(v0.x); x0[1] = bfhi(v0.x); x0[2] = bflo(v0.y); x0[3] = bfhi(v0.y);
    x0[4] = bflo(v0.z); x0[5] = bfhi(v0.z); x0[6] = bflo(v0.w); x0[7] = bfhi(v0.w);

    const float corr = (cnt == 0) ? 0.f : (float)(L - cnt);
    const float inv  = (cnt == 0) ? (1.f / (float)L) : (1.f / (float)cnt);

    ushort* d = dst + (size_t)row * C + ln * 8;
    uint4 o;
    o.x = (unsigned)f2bf((acc[0] - corr * x0[0]) * inv) |
          ((unsigned)f2bf((acc[1] - corr * x0[1]) * inv) << 16);
    o.y = (unsigned)f2bf((acc[2] - corr * x0[2]) * inv) |
          ((unsigned)f2bf((acc[3] - corr * x0[3]) * inv) << 16);
    o.z = (unsigned)f2bf((acc[4] - corr * x0[4]) * inv) |
          ((unsigned)f2bf((acc[5] - corr * x0[5]) * inv) << 16);
    o.w = (unsigned)f2bf((acc[6] - corr * x0[6]) * inv) |
          ((unsigned)f2bf((acc[7] - corr * x0[7]) * inv) << 16);
    *reinterpret_cast<uint4*>(d) = o;
}

// ---------------------------------------------------------------------------
// gather_node (gather2): out[row, chunk*64 .. +64] fp32.
// R4 experiment:
//  (1) chunk is XCD-PINNED: each block reads its physical XCC_ID and
//      prefers chunk = xcc&3, taking a row-group ticket from a per-chunk
//      atomic counter (work-stealing fallback over the other chunks
//      guarantees exact coverage: 4*RBLK tickets == gridDim blocks).
//      Goal: each XCD's L2 holds exactly one 3.2MB source slice, no matter
//      how the dispatcher maps blocks to XCDs.
//  (2) output stores are nontemporal (via ext_vector f32x4): the 50MB write
//      stream is never re-read and must not evict the source slice from L2.
// ---------------------------------------------------------------------------
__global__ __launch_bounds__(256) void gather_node_kernel(
    const ushort* __restrict__ src, const int* __restrict__ idx,
    float* __restrict__ dst, int nrows)
{
    constexpr int CH = 64, NCHUNK = 4;
    constexpr int LPR = CH / 8;        // 8 lanes per row
    constexpr int RPB = 256 / LPR;     // 32 rows per block
    constexpr int RBLK = (N_NODES + RPB - 1) / RPB;   // row-groups per chunk
    const int t = threadIdx.x;

    __shared__ int s_chunk, s_rg;
    if (t == 0) {
        const int xcc = get_xcc_id();
        int c = xcc & (NCHUNK - 1), rg = -1;
#pragma unroll
        for (int i = 0; i < NCHUNK; ++i) {
            const int cc = (xcc + i) & (NCHUNK - 1);
            const int u = atomicAdd(&chunk_cnt_g[cc], 1);
            if (u < RBLK) { c = cc; rg = u; break; }
        }
        s_chunk = c; s_rg = rg;   // rg always found (ticket-count argument)
    }
    __syncthreads();
    const int chunk = s_chunk;
    const int rb    = s_rg * RPB;

    __shared__ int sidx[RPB][33];
#pragma unroll
    for (int i = 0; i < (RPB * L) / 256; ++i) {
        const int flat = i * 256 + t;
        const int r = flat >> 5, l = flat & 31;
        sidx[r][l] = (rb + r < nrows) ? idx[(size_t)(rb + r) * L + l] : 0;
    }
    __syncthreads();

    const int r   = t / LPR;
    const int ch  = chunk * CH + (t % LPR) * 8;
    const int row = rb + r;
    if (row >= nrows) return;

    float acc[8] = {0.f, 0.f, 0.f, 0.f, 0.f, 0.f, 0.f, 0.f};
    int cnt = 0;
#pragma unroll
    for (int l = 0; l < L; ++l) {
        const int id = sidx[r][l];
        cnt += (id > 0) ? 1 : 0;
        const uint4 v = *reinterpret_cast<const uint4*>(
            src + (size_t)id * C + ch);
        acc_uint4(acc, v);
    }
    const uint4 v0 = *reinterpret_cast<const uint4*>(src + ch);  // row 0
    float x0[8];
    x0[0] = bflo(v0.x); x0[1] = bfhi(v0.x); x0[2] = bflo(v0.y); x0[3] = bfhi(v0.y);
    x0[4] = bflo(v0.z); x0[5] = bfhi(v0.z); x0[6] = bflo(v0.w); x0[7] = bfhi(v0.w);

    const float corr = (cnt == 0) ? 0.f : (float)(L - cnt);
    const float inv  = (cnt == 0) ? (1.f / (float)L) : (1.f / (float)cnt);

    float* d = dst + (size_t)row * C + ch;
    f32x4 o0 = {(acc[0] - corr * x0[0]) * inv, (acc[1] - corr * x0[1]) * inv,
                (acc[2] - corr * x0[2]) * inv, (acc[3] - corr * x0[3]) * inv};
    f32x4 o1 = {(acc[4] - corr * x0[4]) * inv, (acc[5] - corr * x0[5]) * inv,
                (acc[6] - corr * x0[6]) * inv, (acc[7] - corr * x0[7]) * inv};
    __builtin_nontemporal_store(o0, reinterpret_cast<f32x4*>(d));
    __builtin_nontemporal_store(o1, reinterpret_cast<f32x4*>(d) + 1);
}

// ---------------------------------------------------------------------------
// MFMA bf16 GEMM: C[M,256] = A[M,256] @ W, W transposed bf16 [n][k].
// Wave tile: 32 rows x 128 cols (2x8 mfma 16x16x32 tiles, B reused across
// the two row-halves -> half the per-wave B traffic of the 16x256 shape).
// grid: (ceil(M/128), 2); blockIdx.y picks the n-half.
// C/D: col=lane&15, row=quad*4+reg (m89-verified layout).
// ---------------------------------------------------------------------------
template <bool RELU>
__global__ __launch_bounds__(256) void gemm_mfma_kernel(
    const ushort* __restrict__ A, int which_w,
    ushort* __restrict__ Cmat, int M)
{
    const ushort* __restrict__ BT = which_w ? W2T_g : W1T_g;
    const int wave  = threadIdx.x >> 6;
    const int lane  = threadIdx.x & 63;
    const int quad  = lane >> 4;
    const int l16   = lane & 15;
    const int base  = (blockIdx.x * 4 + wave) * 32;
    const int nbase = blockIdx.y * 128;

    int m0 = base + l16;      if (m0 > M - 1) m0 = M - 1;
    int m1 = base + 16 + l16; if (m1 > M - 1) m1 = M - 1;

    f32x4 acc[2][8];
    const f32x4 zero = {0.f, 0.f, 0.f, 0.f};
#pragma unroll
    for (int p = 0; p < 2; ++p)
#pragma unroll
        for (int t = 0; t < 8; ++t) acc[p][t] = zero;

    const ushort* a0 = A + (size_t)m0 * C + quad * 8;
    const ushort* a1 = A + (size_t)m1 * C + quad * 8;
    const ushort* br = BT + (size_t)(nbase + l16) * C + quad * 8;

#pragma unroll
    for (int k0 = 0; k0 < C; k0 += 32) {
        const bf16x8 av0 = *reinterpret_cast<const bf16x8*>(a0 + k0);
        const bf16x8 av1 = *reinterpret_cast<const bf16x8*>(a1 + k0);
#pragma unroll
        for (int t = 0; t < 8; ++t) {
            const bf16x8 b = *reinterpret_cast<const bf16x8*>(
                br + (size_t)t * 16 * C + k0);
            acc[0][t] = __builtin_amdgcn_mfma_f32_16x16x32_bf16(av0, b, acc[0][t], 0, 0, 0);
            acc[1][t] = __builtin_amdgcn_mfma_f32_16x16x32_bf16(av1, b, acc[1][t], 0, 0, 0);
        }
    }

#pragma unroll
    for (int p = 0; p < 2; ++p)
#pragma unroll
    for (int t = 0; t < 8; ++t)
#pragma unroll
    for (int r = 0; r < 4; ++r) {
        const int gm = base + p * 16 + quad * 4 + r;
        if (gm < M) {
            float v = acc[p][t][r];
            if (RELU) v = fmaxf(v, 0.f);
            Cmat[(size_t)gm * C + nbase + t * 16 + l16] = f2bf(v);
        }
    }
}

// ---------------------------------------------------------------------------
// Pipeline (gather1 hoisted before GEMM1 -- linearity):
//   xb   = bf16(x)                       [N,256]
//   tmp1 = gather_edge(xb, seq)          [E,256] bf16  (unchunked, 512B/row)
//   edge = relu(tmp1 @ W1)               [E,256] bf16
//   e1   = edge @ W2                     [E,256] bf16  (overwrites tmp1)
//   out  = gather_node(e1, useq)         [N,256] fp32  (XCD-pinned 64ch chunks)
// ws: xb 25.6MB + tmp1 12.8MB + edge 12.8MB = 51.2MB
// ---------------------------------------------------------------------------
extern "C" void kernel_launch(void* const* d_in, const int* in_sizes, int n_in,
                              void* d_out, int out_size, void* d_ws, size_t ws_size,
                              hipStream_t stream) {
    const float* x    = (const float*)d_in[0];
    const int*   seq  = (const int*)d_in[1];
    const int*   useq = (const int*)d_in[2];
    const float* W1   = (const float*)d_in[3];
    const float* W2   = (const float*)d_in[4];
    float* out = (float*)d_out;

    ushort* xb   = (ushort*)d_ws;                    // [N, C] bf16
    ushort* tmp1 = xb + (size_t)N_NODES * C;         // [E, C] bf16 (also e1)
    ushort* edge = tmp1 + (size_t)N_EDGES * C;       // [E, C] bf16

    convert_x_kernel<<<dim3((N_NODES * C) / (256 * 4)), dim3(256), 0, stream>>>(x, xb);
    wconv_kernel<<<dim3(4, 4, 2), dim3(256), 0, stream>>>(W1, W2);

    gather_edge_kernel<<<dim3((N_EDGES + 7) / 8), dim3(256), 0, stream>>>(
        xb, seq, tmp1, N_EDGES);

    const dim3 ggrid((N_EDGES + 127) / 128, 2);
    gemm_mfma_kernel<true><<<ggrid, dim3(256), 0, stream>>>(tmp1, 0, edge, N_EDGES);
    gemm_mfma_kernel<false><<<ggrid, dim3(256), 0, stream>>>(edge, 1, tmp1, N_EDGES);

    const int rblk2 = (N_NODES + 31) / 32;
    gather_node_kernel<<<dim3(4 * rblk2), dim3(256), 0, stream>>>(
        tmp1, useq, out, N_NODES);
}

// Round 8
// 278.610 us; speedup vs baseline: 1.0403x; 1.0403x over previous
//
#include <hip/hip_runtime.h>

// Problem constants (match reference setup_inputs)
constexpr int N_NODES = 50000;
constexpr int N_EDGES = 25000;
constexpr int C = 256;   // IN == OUT == 256 channels
constexpr int L = 32;    // incidence list width

// Transposed bf16 weights in device globals.
__device__ ushort W1T_g[C * C];   // [n][k] bf16
__device__ ushort W2T_g[C * C];   // [n][k] bf16

// Native clang vector types (usable with nontemporal builtins).
typedef __attribute__((ext_vector_type(8))) short bf16x8;
typedef __attribute__((ext_vector_type(4))) float f32x4;

__device__ __forceinline__ ushort f2bf(float f) {
    union { float f; unsigned int u; } c; c.f = f;
    unsigned int r = c.u + 0x7FFFu + ((c.u >> 16) & 1u);   // RNE
    return (ushort)(r >> 16);
}
// bf16 pair unpack: low half = shift, high half = mask (1 VALU op each)
__device__ __forceinline__ float bflo(unsigned int u) {
    union { unsigned int x; float f; } c; c.x = u << 16; return c.f;
}
__device__ __forceinline__ float bfhi(unsigned int u) {
    union { unsigned int x; float f; } c; c.x = u & 0xFFFF0000u; return c.f;
}
__device__ __forceinline__ void acc_uint4(float* acc, const uint4 v) {
    acc[0] += bflo(v.x); acc[1] += bfhi(v.x);
    acc[2] += bflo(v.y); acc[3] += bfhi(v.y);
    acc[4] += bflo(v.z); acc[5] += bfhi(v.z);
    acc[6] += bflo(v.w); acc[7] += bfhi(v.w);
}

// ---------------------------------------------------------------------------
// x [N,256] fp32 -> xb bf16. 4 elems/thread.
// ---------------------------------------------------------------------------
__global__ __launch_bounds__(256) void convert_x_kernel(
    const float* __restrict__ x, ushort* __restrict__ xb)
{
    const size_t i = ((size_t)blockIdx.x * 256 + threadIdx.x) * 4;
    const float4 v = *reinterpret_cast<const float4*>(x + i);
    ushort4 o;
    o.x = f2bf(v.x); o.y = f2bf(v.y); o.z = f2bf(v.z); o.w = f2bf(v.w);
    *reinterpret_cast<ushort4*>(xb + i) = o;
}

// ---------------------------------------------------------------------------
// W [256k,256n] fp32 row-major -> WT [n][k] bf16 (transposed), via LDS tile.
// ---------------------------------------------------------------------------
__global__ __launch_bounds__(256) void wconv_kernel(
    const float* __restrict__ W1, const float* __restrict__ W2)
{
    const float* W  = blockIdx.z ? W2 : W1;
    ushort* WT      = blockIdx.z ? W2T_g : W1T_g;
    __shared__ float t[64][65];
    const int rr = threadIdx.x >> 6;    // 0..3
    const int cc = threadIdx.x & 63;    // 0..63
    const int br = blockIdx.x * 64;     // k tile
    const int bc = blockIdx.y * 64;     // n tile
#pragma unroll
    for (int i = 0; i < 16; ++i) {
        const int row = i * 4 + rr;
        t[row][cc] = W[(size_t)(br + row) * C + bc + cc];
    }
    __syncthreads();
#pragma unroll
    for (int i = 0; i < 16; ++i) {
        const int n = i * 4 + rr;
        WT[(size_t)(bc + n) * C + br + cc] = f2bf(t[cc][n]);
    }
}

// ---------------------------------------------------------------------------
// gather_edge (gather1): tmp1[row,:] = avg over valid slots of xb[seq[row,:],:]
// Half-wave per row, 512B/row granule. BRANCHLESS (id==0 reads row 0, valid;
// subtract the (L-cnt) spurious row-0 contributions afterwards).
// R5: explicit batch-8 load pipelining -- 8 independent uint4 loads issued
// into named registers before any accumulation, to raise per-wave MLP.
// ---------------------------------------------------------------------------
__global__ __launch_bounds__(256) void gather_edge_kernel(
    const ushort* __restrict__ src, const int* __restrict__ idx,
    ushort* __restrict__ dst, int nrows)
{
    const int row = blockIdx.x * 8 + (threadIdx.x >> 5);
    const int ln  = threadIdx.x & 31;
    if (row >= nrows) return;

    const int myid = idx[(size_t)row * L + ln];
    const unsigned long long b = __ballot(myid > 0);
    const unsigned int halfmask = (unsigned int)(b >> (threadIdx.x & 32));
    const int cnt = __popc(halfmask);

    float acc[8] = {0.f, 0.f, 0.f, 0.f, 0.f, 0.f, 0.f, 0.f};
#pragma unroll
    for (int lb = 0; lb < L; lb += 8) {
        uint4 v[8];
#pragma unroll
        for (int j = 0; j < 8; ++j) {
            const int id = __shfl(myid, lb + j, 32);
            v[j] = *reinterpret_cast<const uint4*>(
                src + (size_t)id * C + ln * 8);
        }
#pragma unroll
        for (int j = 0; j < 8; ++j) acc_uint4(acc, v[j]);
    }
    const uint4 v0 = *reinterpret_cast<const uint4*>(src + ln * 8); // row 0
    float x0[8];
    x0[0] = bflo(v0.x); x0[1] = bfhi(v0.x); x0[2] = bflo(v0.y); x0[3] = bfhi(v0.y);
    x0[4] = bflo(v0.z); x0[5] = bfhi(v0.z); x0[6] = bflo(v0.w); x0[7] = bfhi(v0.w);

    const float corr = (cnt == 0) ? 0.f : (float)(L - cnt);
    const float inv  = (cnt == 0) ? (1.f / (float)L) : (1.f / (float)cnt);

    ushort* d = dst + (size_t)row * C + ln * 8;
    uint4 o;
    o.x = (unsigned)f2bf((acc[0] - corr * x0[0]) * inv) |
          ((unsigned)f2bf((acc[1] - corr * x0[1]) * inv) << 16);
    o.y = (unsigned)f2bf((acc[2] - corr * x0[2]) * inv) |
          ((unsigned)f2bf((acc[3] - corr * x0[3]) * inv) << 16);
    o.z = (unsigned)f2bf((acc[4] - corr * x0[4]) * inv) |
          ((unsigned)f2bf((acc[5] - corr * x0[5]) * inv) << 16);
    o.w = (unsigned)f2bf((acc[6] - corr * x0[6]) * inv) |
          ((unsigned)f2bf((acc[7] - corr * x0[7]) * inv) << 16);
    *reinterpret_cast<uint4*>(d) = o;
}

// ---------------------------------------------------------------------------
// gather_node (gather2): out[row, chunk*64 .. +64] fp32.
// R2-proven static chunk mapping (blockIdx&3; R4's atomic tickets REVERTED --
// they cost +10us in block-startup serialization). 128B/row granule.
// R5: explicit batch-8 load pipelining (MLP), nontemporal final stores
// (output is never re-read; keep the 50MB write stream out of L2).
// ---------------------------------------------------------------------------
__global__ __launch_bounds__(256) void gather_node_kernel(
    const ushort* __restrict__ src, const int* __restrict__ idx,
    float* __restrict__ dst, int nrows)
{
    constexpr int CH = 64, NCHUNK = 4;
    constexpr int LPR = CH / 8;        // 8 lanes per row
    constexpr int RPB = 256 / LPR;     // 32 rows per block
    const int chunk = blockIdx.x & (NCHUNK - 1);
    const int rb    = (int)(blockIdx.x / NCHUNK) * RPB;
    const int t     = threadIdx.x;

    __shared__ int sidx[RPB][33];
#pragma unroll
    for (int i = 0; i < (RPB * L) / 256; ++i) {
        const int flat = i * 256 + t;
        const int r = flat >> 5, l = flat & 31;
        sidx[r][l] = (rb + r < nrows) ? idx[(size_t)(rb + r) * L + l] : 0;
    }
    __syncthreads();

    const int r   = t / LPR;
    const int ch  = chunk * CH + (t % LPR) * 8;
    const int row = rb + r;
    if (row >= nrows) return;

    float acc[8] = {0.f, 0.f, 0.f, 0.f, 0.f, 0.f, 0.f, 0.f};
    int cnt = 0;
#pragma unroll
    for (int lb = 0; lb < L; lb += 8) {
        uint4 v[8];
#pragma unroll
        for (int j = 0; j < 8; ++j) {
            const int id = sidx[r][lb + j];
            cnt += (id > 0) ? 1 : 0;
            v[j] = *reinterpret_cast<const uint4*>(
                src + (size_t)id * C + ch);
        }
#pragma unroll
        for (int j = 0; j < 8; ++j) acc_uint4(acc, v[j]);
    }
    const uint4 v0 = *reinterpret_cast<const uint4*>(src + ch);  // row 0
    float x0[8];
    x0[0] = bflo(v0.x); x0[1] = bfhi(v0.x); x0[2] = bflo(v0.y); x0[3] = bfhi(v0.y);
    x0[4] = bflo(v0.z); x0[5] = bfhi(v0.z); x0[6] = bflo(v0.w); x0[7] = bfhi(v0.w);

    const float corr = (cnt == 0) ? 0.f : (float)(L - cnt);
    const float inv  = (cnt == 0) ? (1.f / (float)L) : (1.f / (float)cnt);

    float* d = dst + (size_t)row * C + ch;
    f32x4 o0 = {(acc[0] - corr * x0[0]) * inv, (acc[1] - corr * x0[1]) * inv,
                (acc[2] - corr * x0[2]) * inv, (acc[3] - corr * x0[3]) * inv};
    f32x4 o1 = {(acc[4] - corr * x0[4]) * inv, (acc[5] - corr * x0[5]) * inv,
                (acc[6] - corr * x0[6]) * inv, (acc[7] - corr * x0[7]) * inv};
    __builtin_nontemporal_store(o0, reinterpret_cast<f32x4*>(d));
    __builtin_nontemporal_store(o1, reinterpret_cast<f32x4*>(d) + 1);
}

// ---------------------------------------------------------------------------
// MFMA bf16 GEMM: C[M,256] = A[M,256] @ W, W transposed bf16 [n][k].
// Wave tile: 32 rows x 128 cols (2x8 mfma 16x16x32 tiles, B reused across
// the two row-halves -> half the per-wave B traffic of the 16x256 shape).
// grid: (ceil(M/128), 2); blockIdx.y picks the n-half.
// C/D: col=lane&15, row=quad*4+reg (m89-verified layout).
// ---------------------------------------------------------------------------
template <bool RELU>
__global__ __launch_bounds__(256) void gemm_mfma_kernel(
    const ushort* __restrict__ A, int which_w,
    ushort* __restrict__ Cmat, int M)
{
    const ushort* __restrict__ BT = which_w ? W2T_g : W1T_g;
    const int wave  = threadIdx.x >> 6;
    const int lane  = threadIdx.x & 63;
    const int quad  = lane >> 4;
    const int l16   = lane & 15;
    const int base  = (blockIdx.x * 4 + wave) * 32;
    const int nbase = blockIdx.y * 128;

    int m0 = base + l16;      if (m0 > M - 1) m0 = M - 1;
    int m1 = base + 16 + l16; if (m1 > M - 1) m1 = M - 1;

    f32x4 acc[2][8];
    const f32x4 zero = {0.f, 0.f, 0.f, 0.f};
#pragma unroll
    for (int p = 0; p < 2; ++p)
#pragma unroll
        for (int t = 0; t < 8; ++t) acc[p][t] = zero;

    const ushort* a0 = A + (size_t)m0 * C + quad * 8;
    const ushort* a1 = A + (size_t)m1 * C + quad * 8;
    const ushort* br = BT + (size_t)(nbase + l16) * C + quad * 8;

#pragma unroll
    for (int k0 = 0; k0 < C; k0 += 32) {
        const bf16x8 av0 = *reinterpret_cast<const bf16x8*>(a0 + k0);
        const bf16x8 av1 = *reinterpret_cast<const bf16x8*>(a1 + k0);
#pragma unroll
        for (int t = 0; t < 8; ++t) {
            const bf16x8 b = *reinterpret_cast<const bf16x8*>(
                br + (size_t)t * 16 * C + k0);
            acc[0][t] = __builtin_amdgcn_mfma_f32_16x16x32_bf16(av0, b, acc[0][t], 0, 0, 0);
            acc[1][t] = __builtin_amdgcn_mfma_f32_16x16x32_bf16(av1, b, acc[1][t], 0, 0, 0);
        }
    }

#pragma unroll
    for (int p = 0; p < 2; ++p)
#pragma unroll
    for (int t = 0; t < 8; ++t)
#pragma unroll
    for (int r = 0; r < 4; ++r) {
        const int gm = base + p * 16 + quad * 4 + r;
        if (gm < M) {
            float v = acc[p][t][r];
            if (RELU) v = fmaxf(v, 0.f);
            Cmat[(size_t)gm * C + nbase + t * 16 + l16] = f2bf(v);
        }
    }
}

// ---------------------------------------------------------------------------
// Pipeline (gather1 hoisted before GEMM1 -- linearity):
//   xb   = bf16(x)                       [N,256]
//   tmp1 = gather_edge(xb, seq)          [E,256] bf16  (unchunked, 512B/row)
//   edge = relu(tmp1 @ W1)               [E,256] bf16
//   e1   = edge @ W2                     [E,256] bf16  (overwrites tmp1)
//   out  = gather_node(e1, useq)         [N,256] fp32  (4x64ch chunks)
// ws: xb 25.6MB + tmp1 12.8MB + edge 12.8MB = 51.2MB
// ---------------------------------------------------------------------------
extern "C" void kernel_launch(void* const* d_in, const int* in_sizes, int n_in,
                              void* d_out, int out_size, void* d_ws, size_t ws_size,
                              hipStream_t stream) {
    const float* x    = (const float*)d_in[0];
    const int*   seq  = (const int*)d_in[1];
    const int*   useq = (const int*)d_in[2];
    const float* W1   = (const float*)d_in[3];
    const float* W2   = (const float*)d_in[4];
    float* out = (float*)d_out;

    ushort* xb   = (ushort*)d_ws;                    // [N, C] bf16
    ushort* tmp1 = xb + (size_t)N_NODES * C;         // [E, C] bf16 (also e1)
    ushort* edge = tmp1 + (size_t)N_EDGES * C;       // [E, C] bf16

    convert_x_kernel<<<dim3((N_NODES * C) / (256 * 4)), dim3(256), 0, stream>>>(x, xb);
    wconv_kernel<<<dim3(4, 4, 2), dim3(256), 0, stream>>>(W1, W2);

    gather_edge_kernel<<<dim3((N_EDGES + 7) / 8), dim3(256), 0, stream>>>(
        xb, seq, tmp1, N_EDGES);

    const dim3 ggrid((N_EDGES + 127) / 128, 2);
    gemm_mfma_kernel<true><<<ggrid, dim3(256), 0, stream>>>(tmp1, 0, edge, N_EDGES);
    gemm_mfma_kernel<false><<<ggrid, dim3(256), 0, stream>>>(edge, 1, tmp1, N_EDGES);

    const int rblk2 = (N_NODES + 31) / 32;
    gather_node_kernel<<<dim3(4 * rblk2), dim3(256), 0, stream>>>(
        tmp1, useq, out, N_NODES);
}